// Round 6
// baseline (71.932 us; speedup 1.0000x reference)
//
#include <hip/hip_runtime.h>
#include <math.h>

#pragma clang fp contract(off)

#define TILE 16
#define CELL 64              // bin cell = 64x64 px = 4x4 tiles
#define NSEG 4               // triangle-range segments per cell (keeps order)
#define SEGCAP 960           // u16 entries per (cell,seg) list
#define LCAP 1024            // LDS-staged records per batch

// rec (16 dwords): [0]=bx [1]=by [2]=cx-bx [3]=cy-by | [4]=cx [5]=cy [6]=ax-cx [7]=ay-cy
//                  [8]=ax [9]=ay [10]=bx-ax [11]=by-ay | [12]=inv(0 if invalid) [13..15]=i0,i1,i2
__global__ __launch_bounds__(256) void prep(
    const float* __restrict__ uv, const int* __restrict__ faces,
    float* __restrict__ recs, int nTri)
{
    const int f = blockIdx.x * 256 + threadIdx.x;
    if (f >= nTri) return;
    const int i0 = faces[3 * f], i1 = faces[3 * f + 1], i2 = faces[3 * f + 2];
    const float ax = uv[2 * i0], ay = uv[2 * i0 + 1];
    const float bx = uv[2 * i1], by = uv[2 * i1 + 1];
    const float cx = uv[2 * i2], cy = uv[2 * i2 + 1];
    const float area = (bx - ax) * (cy - ay) - (by - ay) * (cx - ax);  // exact ref op
    const bool valid = fabsf(area) > 1e-9f;
    float* r = recs + 16 * f;
    r[0] = bx; r[1] = by; r[2]  = cx - bx; r[3]  = cy - by;
    r[4] = cx; r[5] = cy; r[6]  = ax - cx; r[7]  = ay - cy;
    r[8] = ax; r[9] = ay; r[10] = bx - ax; r[11] = by - ay;
    r[12] = valid ? 1.0f / area : 0.f;
    ((int*)r)[13] = i0; ((int*)r)[14] = i1; ((int*)r)[15] = i2;
}

// max over rect of s*w_edge >= -eps ? (affine -> max at a corner); conservative.
__device__ __forceinline__ bool edgeMayPass(
    float qx, float qy, float ex, float ey, float s,
    float rx0, float rx1, float ry0, float ry1)
{
    const float A = s * ex;
    const float B = -s * ey;
    const float fy = A * ((A >= 0.f ? ry1 : ry0) - qy);
    const float fx = B * ((B >= 0.f ? rx1 : rx0) - qx);
    return (fy + fx) >= -1e-5f;
}

// Exact (conservative-margin) triangle-vs-rect: bbox axes + 3 edge axes.
__device__ __forceinline__ bool satKeep(
    const float4 r0, const float4 r1, const float4 r2, const float inv,
    float rx0, float rx1, float ry0, float ry1)
{
    if (inv == 0.f) return false;
    const float xmn = fminf(r2.x, fminf(r0.x, r1.x));
    const float xmx = fmaxf(r2.x, fmaxf(r0.x, r1.x));
    const float ymn = fminf(r2.y, fminf(r0.y, r1.y));
    const float ymx = fmaxf(r2.y, fmaxf(r0.y, r1.y));
    if (!((xmn <= rx1) & (xmx >= rx0) & (ymn <= ry1) & (ymx >= ry0))) return false;
    const float s = (inv >= 0.f) ? 1.f : -1.f;
    return edgeMayPass(r0.x, r0.y, r0.z, r0.w, s, rx0, rx1, ry0, ry1)
        && edgeMayPass(r1.x, r1.y, r1.z, r1.w, s, rx0, rx1, ry0, ry1)
        && edgeMayPass(r2.x, r2.y, r2.z, r2.w, s, rx0, rx1, ry0, ry1);
}

__global__ __launch_bounds__(256) void bin_cells(
    const float* __restrict__ recs, unsigned short* __restrict__ lists,
    int* __restrict__ counts, int res, int nTri, int nCellX)
{
    __shared__ int waveCnt[4];
    const int cell = blockIdx.x >> 2;       // NSEG==4
    const int seg  = blockIdx.x & 3;
    const int cellX = cell % nCellX, cellY = cell / nCellX;
    const float rf = (float)res;
    const float rx0 = ((float)(cellX * CELL) - 1.5f) / rf;
    const float rx1 = ((float)(cellX * CELL + CELL) + 1.5f) / rf;
    const float ry0 = ((float)(cellY * CELL) - 1.5f) / rf;
    const float ry1 = ((float)(cellY * CELL + CELL) + 1.5f) / rf;

    const int segLen = (nTri + NSEG - 1) / NSEG;
    const int s0 = seg * segLen, s1 = min(nTri, s0 + segLen);
    const int lane = threadIdx.x & 63, wv = threadIdx.x >> 6;
    unsigned short* myList = lists + (size_t)(cell * NSEG + seg) * SEGCAP;

    int cnt = 0;
    for (int base = s0; base < s1; base += 256) {
        const int t = base + threadIdx.x;
        bool keep = false;
        if (t < s1) {
            const float4* R = (const float4*)(recs + 16 * t);   // coalesced 64B/lane
            const float4 r0 = R[0], r1 = R[1], r2 = R[2], r3 = R[3];
            keep = satKeep(r0, r1, r2, r3.x, rx0, rx1, ry0, ry1);
        }
        const unsigned long long m = __ballot(keep);
        if (lane == 0) waveCnt[wv] = __popcll(m);
        __syncthreads();
        int off = 0;
        #pragma unroll
        for (int w = 0; w < 4; ++w) if (w < wv) off += waveCnt[w];
        const int tot = waveCnt[0] + waveCnt[1] + waveCnt[2] + waveCnt[3];
        const int pre = __popcll(m & ((1ull << lane) - 1ull));
        if (keep) {
            const int slot = cnt + off + pre;
            if (slot < SEGCAP) myList[slot] = (unsigned short)t;
        }
        __syncthreads();
        cnt += tot;     // may exceed SEGCAP -> bake falls back to range scan
    }
    if (threadIdx.x == 0) counts[cell * NSEG + seg] = cnt;
}

__global__ __launch_bounds__(256) void bake_tile(
    const float* __restrict__ recs, const unsigned short* __restrict__ lists,
    const int* __restrict__ counts, const float* __restrict__ attr,
    float* __restrict__ out, int res, int nTri, int nCellX)
{
    __shared__ float4 L0[LCAP], L1[LCAP], L2[LCAP], L3[LCAP];   // SoA: write-conflict friendly
    __shared__ int waveCnt[4];

    const int tx = threadIdx.x & 15, ty = threadIdx.x >> 4;
    const int pxi = blockIdx.x * TILE + tx;
    const int pyi = blockIdx.y * TILE + ty;
    const bool inb = (pxi < res) && (pyi < res);
    const float rf = (float)res;
    const float px = ((float)pxi + 0.5f) / rf;   // exact reference op
    const float py = ((float)pyi + 0.5f) / rf;

    const float rx0 = ((float)(blockIdx.x * TILE) - 1.0f) / rf;
    const float rx1 = ((float)(blockIdx.x * TILE + TILE) + 1.0f) / rf;
    const float ry0 = ((float)(blockIdx.y * TILE) - 1.0f) / rf;
    const float ry1 = ((float)(blockIdx.y * TILE + TILE) + 1.0f) / rf;

    const int cell = (blockIdx.y / (CELL / TILE)) * nCellX + (blockIdx.x / (CELL / TILE));
    const int segLen = (nTri + NSEG - 1) / NSEG;
    const int lane = threadIdx.x & 63, wv = threadIdx.x >> 6;

    bool hit = false;
    float g0 = 0.f, g1 = 0.f, g2 = 0.f;
    int ji0 = 0, ji1 = 0, ji2 = 0;

    int s = 0, pos = 0;
    int scount = 0, total = 0, sBase = 0;
    bool useList = true, segLoaded = false;

    while (true) {
        // ---- fill LDS with tile-SAT survivors, ascending tri order ----
        int listLen = 0;
        bool over = false;
        while (s < NSEG) {
            if (!segLoaded) {
                scount = counts[cell * NSEG + s];      // uniform
                useList = (scount <= SEGCAP);
                sBase = s * segLen;
                const int sEnd = min(nTri, sBase + segLen);
                total = useList ? scount : (sEnd - sBase);
                segLoaded = true;
            }
            if (pos >= total) { s++; pos = 0; segLoaded = false; continue; }
            const int n = min(256, total - pos);
            bool keep = false;
            float4 r0, r1, r2, r3;
            if (threadIdx.x < n) {
                const int idx = pos + threadIdx.x;
                const int t = useList
                    ? (int)lists[(size_t)(cell * NSEG + s) * SEGCAP + idx]
                    : (sBase + idx);
                const float4* R = (const float4*)(recs + 16 * t);
                r0 = R[0]; r1 = R[1]; r2 = R[2]; r3 = R[3];
                keep = satKeep(r0, r1, r2, r3.x, rx0, rx1, ry0, ry1);
            }
            const unsigned long long m = __ballot(keep);
            if (lane == 0) waveCnt[wv] = __popcll(m);
            __syncthreads();
            int off = 0;
            #pragma unroll
            for (int w = 0; w < 4; ++w) if (w < wv) off += waveCnt[w];
            const int tot = waveCnt[0] + waveCnt[1] + waveCnt[2] + waveCnt[3];
            if (listLen + tot > LCAP) { over = true; break; }   // uniform; resume at same pos
            const int pre = __popcll(m & ((1ull << lane) - 1ull));
            if (keep) {
                const int slot = listLen + off + pre;
                L0[slot] = r0; L1[slot] = r1; L2[slot] = r2; L3[slot] = r3;
            }
            __syncthreads();            // records visible + waveCnt reusable
            listLen += tot; pos += n;
        }

        // ---- scan staged candidates in order, first hit wins ----
        if (listLen > 0) {
            const int last = listLen - 1;
            for (int i = 0; i < listLen; i += 4) {
                if (!__any(inb && !hit)) break;
                const int k1 = min(i + 1, last), k2 = min(i + 2, last), k3 = min(i + 3, last);
                const float4 A0 = L0[i],  A1 = L1[i],  A2 = L2[i],  A3 = L3[i];
                const float4 B0 = L0[k1], B1 = L1[k1], B2 = L2[k1], B3 = L3[k1];
                const float4 C0 = L0[k2], C1 = L1[k2], C2 = L2[k2], C3 = L3[k2];
                const float4 D0 = L0[k3], D1 = L1[k3], D2 = L2[k3], D3 = L3[k3];
                #define TESTC(q0, q1, q2, q3)                                      \
                    if (inb && !hit) {                                             \
                        const float w0 = q0.z * (py - q0.y) - q0.w * (px - q0.x);  \
                        const float w1 = q1.z * (py - q1.y) - q1.w * (px - q1.x);  \
                        const float w2 = q2.z * (py - q2.y) - q2.w * (px - q2.x);  \
                        const float iv = q3.x;                                     \
                        const float b0 = w0 * iv, b1 = w1 * iv, b2 = w2 * iv;      \
                        if ((b0 >= 0.f) & (b1 >= 0.f) & (b2 >= 0.f)) {             \
                            hit = true; g0 = b0; g1 = b1; g2 = b2;                 \
                            ji0 = __float_as_int(q3.y);                            \
                            ji1 = __float_as_int(q3.z);                            \
                            ji2 = __float_as_int(q3.w);                            \
                        }                                                          \
                    }
                TESTC(A0, A1, A2, A3)
                TESTC(B0, B1, B2, B3)
                TESTC(C0, C1, C2, C3)
                TESTC(D0, D1, D2, D3)
                #undef TESTC
            }
        }
        const bool fin = __syncthreads_and(hit || !inb);   // also fences LDS reuse
        if (fin) break;
        if (!over && s >= NSEG) break;                     // exhausted; some pixels empty
    }

    if (inb) {
        float o0 = 0.f, o1 = 0.f, o2 = 0.f;
        if (hit) {
            o0 = g0 * attr[3 * ji0 + 0] + g1 * attr[3 * ji1 + 0] + g2 * attr[3 * ji2 + 0];
            o1 = g0 * attr[3 * ji0 + 1] + g1 * attr[3 * ji1 + 1] + g2 * attr[3 * ji2 + 1];
            o2 = g0 * attr[3 * ji0 + 2] + g1 * attr[3 * ji1 + 2] + g2 * attr[3 * ji2 + 2];
        }
        const int o = (pyi * res + pxi) * 3;
        out[o + 0] = o0; out[o + 1] = o1; out[o + 2] = o2;
    }
}

// ---- fallback (tiny workspace / huge nTri): proven-correct wave-per-pixel scan ----
__global__ __launch_bounds__(256) void bake_wave(
    const float* __restrict__ uv, const int* __restrict__ faces,
    const float* __restrict__ attr, float* __restrict__ out,
    int res, int nTri)
{
    const int lane = threadIdx.x & 63;
    const int wid  = blockIdx.x * (blockDim.x >> 6) + (threadIdx.x >> 6);
    const int npix = res * res;
    if (wid >= npix) return;
    const int pyi = wid / res, pxi = wid - pyi * res;
    const float rf = (float)res;
    const float px = ((float)pxi + 0.5f) / rf, py = ((float)pyi + 0.5f) / rf;
    for (int base = 0; base < nTri; base += 64) {
        const int t = base + lane;
        bool hit = false; float b0 = 0, b1 = 0, b2 = 0; int i0 = 0, i1 = 0, i2 = 0;
        if (t < nTri) {
            i0 = faces[3 * t]; i1 = faces[3 * t + 1]; i2 = faces[3 * t + 2];
            const float ax = uv[2 * i0], ay = uv[2 * i0 + 1];
            const float bx = uv[2 * i1], by = uv[2 * i1 + 1];
            const float cx = uv[2 * i2], cy = uv[2 * i2 + 1];
            const float area = (bx - ax) * (cy - ay) - (by - ay) * (cx - ax);
            if (fabsf(area) > 1e-9f) {
                const float inv = 1.0f / area;
                b0 = ((cx - bx) * (py - by) - (cy - by) * (px - bx)) * inv;
                b1 = ((ax - cx) * (py - cy) - (ay - cy) * (px - cx)) * inv;
                b2 = ((bx - ax) * (py - ay) - (by - ay) * (px - ax)) * inv;
                hit = (b0 >= 0.f) & (b1 >= 0.f) & (b2 >= 0.f);
            }
        }
        const unsigned long long m = __ballot(hit);
        if (m) {
            const int src = (int)__builtin_ctzll(m);
            b0 = __shfl(b0, src, 64); b1 = __shfl(b1, src, 64); b2 = __shfl(b2, src, 64);
            const int J0 = __shfl(i0, src, 64), J1 = __shfl(i1, src, 64), J2 = __shfl(i2, src, 64);
            if (lane == 0) {
                const int o = wid * 3;
                out[o + 0] = b0 * attr[3 * J0] + b1 * attr[3 * J1] + b2 * attr[3 * J2];
                out[o + 1] = b0 * attr[3 * J0 + 1] + b1 * attr[3 * J1 + 1] + b2 * attr[3 * J2 + 1];
                out[o + 2] = b0 * attr[3 * J0 + 2] + b1 * attr[3 * J1 + 2] + b2 * attr[3 * J2 + 2];
            }
            return;
        }
    }
    if (lane == 0) { const int o = wid * 3; out[o] = 0.f; out[o + 1] = 0.f; out[o + 2] = 0.f; }
}

extern "C" void kernel_launch(void* const* d_in, const int* in_sizes, int n_in,
                              void* d_out, int out_size, void* d_ws, size_t ws_size,
                              hipStream_t stream) {
    const float* attr  = (const float*)d_in[0];
    const float* uv    = (const float*)d_in[1];
    const int*   faces = (const int*)d_in[2];
    float*       out   = (float*)d_out;

    const int nTri = in_sizes[2] / 3;
    const int res  = (int)(sqrt((double)(out_size / 3)) + 0.5);
    const int npix = res * res;

    const int nCellX = (res + CELL - 1) / CELL;
    const int nCells = nCellX * nCellX;
    const size_t recsBytes = (size_t)nTri * 64;
    const size_t cntBytes  = (size_t)nCells * NSEG * sizeof(int);
    const size_t listBytes = (size_t)nCells * NSEG * SEGCAP * sizeof(unsigned short);

    if (nTri <= 65536 && ws_size >= recsBytes + cntBytes + listBytes) {
        float* recs = (float*)d_ws;
        int*   counts = (int*)((char*)d_ws + recsBytes);
        unsigned short* lists = (unsigned short*)((char*)d_ws + recsBytes + cntBytes);
        prep<<<(nTri + 255) / 256, 256, 0, stream>>>(uv, faces, recs, nTri);
        bin_cells<<<nCells * NSEG, 256, 0, stream>>>(recs, lists, counts, res, nTri, nCellX);
        dim3 grid((res + TILE - 1) / TILE, (res + TILE - 1) / TILE);
        bake_tile<<<grid, 256, 0, stream>>>(recs, lists, counts, attr, out, res, nTri, nCellX);
    } else {
        bake_wave<<<(npix + 3) / 4, 256, 0, stream>>>(uv, faces, attr, out, res, nTri);
    }
}